// Round 1
// baseline (1901.419 us; speedup 1.0000x reference)
//
#include <hip/hip_runtime.h>
#include <hip/hip_bf16.h>
#include <stdint.h>

#define BB 4
#define NN 16384
#define SS 1024
#define KSAMP 64
#define DD 256
#define CIN 259
#define HH 512
#define R2C 0.04f

// workspace offsets (bytes, all 256-aligned)
#define OFF_PTS  0ull            // bf16 pointsT [B][N][256]  33,554,432
#define OFF_Q    33554432ull     // f32 point norms [B][N]       262,144
#define OFF_W1P  33816576ull     // bf16 packed w1               294,912
#define OFF_W2P  34111488ull     // bf16 packed w2               524,288
#define OFF_CX   34635776ull     // f32 centers x [4096]
#define OFF_CY   34652160ull
#define OFF_CZ   34668544ull
#define OFF_BIDX 34684928ull     // int group idx [4096][64]   1,048,576

typedef __attribute__((ext_vector_type(8))) short bf16x8;
typedef __attribute__((ext_vector_type(4))) short bf16x4;
typedef __attribute__((ext_vector_type(4))) float f32x4;

__device__ __forceinline__ unsigned short f2bf(float f) {
    unsigned u = __float_as_uint(f);
    u = u + 0x7fffu + ((u >> 16) & 1u);   // round-to-nearest-even
    return (unsigned short)(u >> 16);
}

// ---------------------------------------------------------------------------
// Kernel 1: fused FPS (blocks 0..3) + points transpose->bf16 (4..1027)
//           + point norms (1028..1091) + weight packing (1092,1093)
// ---------------------------------------------------------------------------
__global__ __launch_bounds__(1024) void k_prep(const float* __restrict__ xyz,
                                               const float* __restrict__ pts,
                                               const float* __restrict__ w1,
                                               const float* __restrict__ w2,
                                               unsigned char* __restrict__ ws)
{
    __shared__ __align__(16) unsigned char smem[64 * 264 * 2];
    const int blk = blockIdx.x;
    const int t   = threadIdx.x;

    if (blk < 4) {
        // ---------------- FPS, batch b = blk -------------------------------
        const int b = blk;
        const float* xb = xyz + (size_t)b * 3 * NN;
        float x[16], y[16], z[16], d[16];
        const int base = t * 16;
        const float4* xv = (const float4*)(xb + base);
        const float4* yv = (const float4*)(xb + NN + base);
        const float4* zv = (const float4*)(xb + 2 * NN + base);
#pragma unroll
        for (int i = 0; i < 4; i++) {
            float4 a = xv[i]; x[4*i]=a.x; x[4*i+1]=a.y; x[4*i+2]=a.z; x[4*i+3]=a.w;
            float4 c = yv[i]; y[4*i]=c.x; y[4*i+1]=c.y; y[4*i+2]=c.z; y[4*i+3]=c.w;
            float4 e = zv[i]; z[4*i]=e.x; z[4*i+1]=e.y; z[4*i+2]=e.z; z[4*i+3]=e.w;
        }
#pragma unroll
        for (int i = 0; i < 16; i++) d[i] = 1e10f;

        float* sC    = (float*)smem;         // [3] centroid
        float* sWMax = (float*)smem + 4;     // [16]
        int*   sWin  = (int*)((float*)smem + 20);
        float* cxs = (float*)(ws + OFF_CX);
        float* cys = (float*)(ws + OFF_CY);
        float* czs = (float*)(ws + OFF_CZ);

        // initial farthest = b (b < 16 -> owner thread 0)
        if (t == (b >> 4)) {
#pragma unroll
            for (int k = 0; k < 16; k++)
                if ((b & 15) == k) { sC[0] = x[k]; sC[1] = y[k]; sC[2] = z[k]; }
        }
        __syncthreads();

        for (int it = 0; it < SS; ++it) {
            const float cx = sC[0], cy = sC[1], cz = sC[2];
            if (t == 0) {
                cxs[(b << 10) + it] = cx;
                cys[(b << 10) + it] = cy;
                czs[(b << 10) + it] = cz;
                *sWin = 0x7fffffff;
            }
            if (it == SS - 1) break;

            float bl = -1.0f;
#pragma unroll
            for (int k = 0; k < 16; k++) {
                float dx = __fsub_rn(x[k], cx);
                float dy = __fsub_rn(y[k], cy);
                float dz = __fsub_rn(z[k], cz);
                float s  = __fadd_rn(__fadd_rn(__fmul_rn(dx, dx), __fmul_rn(dy, dy)),
                                     __fmul_rn(dz, dz));
                float nd = fminf(d[k], s);
                d[k] = nd;
                bl = fmaxf(bl, nd);
            }
            float bm = bl;
#pragma unroll
            for (int off = 32; off; off >>= 1) bm = fmaxf(bm, __shfl_xor(bm, off));
            if ((t & 63) == 0) sWMax[t >> 6] = bm;
            __syncthreads();

            float gm = sWMax[0];
#pragma unroll
            for (int wv = 1; wv < 16; wv++) gm = fmaxf(gm, sWMax[wv]);

            if (bl == gm) {
                int cand = 0x7fffffff;
#pragma unroll
                for (int k = 15; k >= 0; k--) if (d[k] == gm) cand = base + k;
                atomicMin(sWin, cand);
            }
            __syncthreads();
            const int w = *sWin;
            if (t == (w >> 4)) {
                const int wk = w & 15;
#pragma unroll
                for (int k = 0; k < 16; k++)
                    if (wk == k) { sC[0] = x[k]; sC[1] = y[k]; sC[2] = z[k]; }
            }
            __syncthreads();
        }
    } else if (blk < 1028) {
        // ---------------- transpose points -> bf16 rows --------------------
        const int tb = blk - 4;
        const int b  = tb >> 8;
        const int n0 = (tb & 255) << 6;       // 64 points per tile
        unsigned short* sT = (unsigned short*)smem;  // [64][264]
        const int tn = t & 63, tc = t >> 6;   // tc 0..15
        for (int cc = tc; cc < 256; cc += 16) {
            float v = pts[((size_t)(b * 256 + cc)) * NN + n0 + tn];
            sT[tn * 264 + cc] = f2bf(v);
        }
        __syncthreads();
        unsigned short* ptsT = (unsigned short*)(ws + OFF_PTS);
        const int r = t >> 4, part = t & 15;  // 16 shorts per thread
        size_t ob = (((size_t)b * NN) + n0 + r) * 256 + part * 16;
        bf16x8* dst = (bf16x8*)(ptsT + ob);
        const bf16x8* src = (const bf16x8*)(sT + r * 264 + part * 16);
        dst[0] = src[0];
        dst[1] = src[1];
    } else if (blk < 1092) {
        // ---------------- point squared norms ------------------------------
        const int qb = blk - 1028;
        const int b = qb >> 4;
        const int n = ((qb & 15) << 10) + t;
        const float* xb = xyz + (size_t)b * 3 * NN;
        float X = xb[n], Y = xb[NN + n], Z = xb[2 * NN + n];
        float q = __fadd_rn(__fadd_rn(__fmul_rn(X, X), __fmul_rn(Y, Y)), __fmul_rn(Z, Z));
        ((float*)(ws + OFF_Q))[b * NN + n] = q;
    } else if (blk == 1092) {
        // ---------------- pack w1 into MFMA-B fragment order ---------------
        // element e = ((nt*9 + kt)*64 + lane)*8 + j
        // k = kt*32 + 4*(lane>>4) + (j&3) + 16*(j>>2); n = nt*16 + (lane&15)
        // feature permutation: cols 0..255 = points(c=3..258), 256..258 = norm(c=0..2)
        unsigned short* w1p = (unsigned short*)(ws + OFF_W1P);
        for (int e = t; e < 32 * 9 * 64 * 8; e += 1024) {
            int j = e & 7, lane = (e >> 3) & 63, rest = e >> 9;
            int kt = rest % 9, nt = rest / 9;
            int kk = kt * 32 + 4 * (lane >> 4) + (j & 3) + 16 * (j >> 2);
            int o  = nt * 16 + (lane & 15);
            float v = 0.f;
            if (kk < CIN) {
                int c = (kk < 256) ? (kk + 3) : (kk - 256);
                v = w1[o * CIN + c];
            }
            w1p[e] = f2bf(v);
        }
    } else if (blk == 1093) {
        unsigned short* w2p = (unsigned short*)(ws + OFF_W2P);
        for (int e = t; e < 32 * 16 * 64 * 8; e += 1024) {
            int j = e & 7, lane = (e >> 3) & 63, rest = e >> 9;
            int kt = rest & 15, nt = rest >> 4;
            int kk = kt * 32 + 4 * (lane >> 4) + (j & 3) + 16 * (j >> 2);
            int o  = nt * 16 + (lane & 15);
            w2p[e] = f2bf(w2[o * 512 + kk]);
        }
    }
}

// ---------------------------------------------------------------------------
// Kernel 2: ball query — one wave per query, ordered first-64 selection
// ---------------------------------------------------------------------------
__global__ __launch_bounds__(256) void k_ball(const float* __restrict__ xyz,
                                              unsigned char* __restrict__ ws)
{
    const int s    = (blockIdx.x << 2) + (threadIdx.x >> 6);  // 0..4095
    const int lane = threadIdx.x & 63;
    const int b    = s >> 10;
    const float* Q  = (const float*)(ws + OFF_Q) + b * NN;
    const float cx = ((const float*)(ws + OFF_CX))[s];
    const float cy = ((const float*)(ws + OFF_CY))[s];
    const float cz = ((const float*)(ws + OFF_CZ))[s];
    const float qc = __fadd_rn(__fadd_rn(__fmul_rn(cx, cx), __fmul_rn(cy, cy)),
                               __fmul_rn(cz, cz));
    const float* xb = xyz + (size_t)b * 3 * NN;
    int* gi = (int*)(ws + OFF_BIDX) + s * 64;

    int collected = 0;
    int first = -1;
    for (int c = 0; c < 256; c++) {
        const int n = (c << 6) + lane;
        float px = xb[n], py = xb[NN + n], pz = xb[2 * NN + n], qj = Q[n];
        float dot = __fadd_rn(__fadd_rn(__fmul_rn(cx, px), __fmul_rn(cy, py)),
                              __fmul_rn(cz, pz));
        float r = __fsub_rn(__fadd_rn(qc, qj), __fmul_rn(2.0f, dot));
        bool valid = !(r > R2C);
        unsigned long long m = __ballot(valid);
        if (m) {
            if (first < 0) first = (c << 6) + __builtin_ctzll(m);
            int rank = __popcll(m & ((1ull << lane) - 1ull));
            int slot = collected + rank;
            if (valid && slot < 64) gi[slot] = n;
            collected += __popcll(m);
            if (collected >= 64) break;
        }
    }
    if (collected < 64) {
        for (int k = collected + lane; k < 64; k += 64) gi[k] = first;
    }
}

// ---------------------------------------------------------------------------
// Kernel 3: gather + MLP(259->512->512, swish) + mean over 64 samples
// one block per (b, s); 8 waves; bf16 MFMA 16x16x32
// ---------------------------------------------------------------------------
__global__ __launch_bounds__(512) void k_mlp(const float* __restrict__ xyz,
                                             const float* __restrict__ b1,
                                             const float* __restrict__ b2,
                                             const unsigned char* __restrict__ ws,
                                             float* __restrict__ out)
{
    __shared__ __align__(16) unsigned short sFeat[64 * 296];  // 37,888 B
    __shared__ __align__(16) unsigned short sH1[64 * 520];    // 66,560 B
    __shared__ int sIdx[64];

    const int sblk = blockIdx.x;          // 0..4095
    const int b = sblk >> 10, sq = sblk & 1023;
    const int t = threadIdx.x;

    const int* gi = (const int*)(ws + OFF_BIDX) + sblk * 64;
    if (t < 64) sIdx[t] = gi[t];
    __syncthreads();

    // gather point features (cols 0..255)
    {
        const unsigned short* ptsT = (const unsigned short*)(ws + OFF_PTS);
        const int k = t >> 3, part = t & 7;
        const int n = sIdx[k];
        const bf16x8* src = (const bf16x8*)(ptsT + (((size_t)b * NN + n) * 256 + part * 32));
        bf16x8* dst = (bf16x8*)(sFeat + k * 296 + part * 32);
#pragma unroll
        for (int j = 0; j < 4; j++) dst[j] = src[j];
    }
    // grouped_norm (cols 256..258) + zero pad (259..287)
    if (t < 64) {
        const int n = sIdx[t];
        const float* xb = xyz + (size_t)b * 3 * NN;
        const float cx = ((const float*)(ws + OFF_CX))[sblk];
        const float cy = ((const float*)(ws + OFF_CY))[sblk];
        const float cz = ((const float*)(ws + OFF_CZ))[sblk];
        sFeat[t * 296 + 256] = f2bf(__fsub_rn(xb[n], cx));
        sFeat[t * 296 + 257] = f2bf(__fsub_rn(xb[NN + n], cy));
        sFeat[t * 296 + 258] = f2bf(__fsub_rn(xb[2 * NN + n], cz));
#pragma unroll
        for (int c = 259; c < 288; c++) sFeat[t * 296 + c] = 0;
    }
    __syncthreads();

    const int wv = t >> 6, lane = t & 63;
    const int l15 = lane & 15, g = lane >> 4;

    f32x4 acc[4][4];
#pragma unroll
    for (int i = 0; i < 4; i++)
#pragma unroll
        for (int j = 0; j < 4; j++) acc[i][j] = (f32x4){0.f, 0.f, 0.f, 0.f};

    // ---- layer 1: K = 288 (9 ktiles) ----
    const bf16x8* w1v = (const bf16x8*)(ws + OFF_W1P);
    for (int kt = 0; kt < 9; kt++) {
        bf16x8 af[4];
#pragma unroll
        for (int mt = 0; mt < 4; mt++) {
            const unsigned short* p = sFeat + (mt * 16 + l15) * 296 + kt * 32 + 4 * g;
            bf16x4 lo = *(const bf16x4*)p;
            bf16x4 hi = *(const bf16x4*)(p + 16);
            af[mt] = __builtin_shufflevector(lo, hi, 0, 1, 2, 3, 4, 5, 6, 7);
        }
        bf16x8 bfr[4];
#pragma unroll
        for (int nti = 0; nti < 4; nti++)
            bfr[nti] = w1v[((wv * 4 + nti) * 9 + kt) * 64 + lane];
#pragma unroll
        for (int mt = 0; mt < 4; mt++)
#pragma unroll
            for (int nti = 0; nti < 4; nti++)
                acc[mt][nti] = __builtin_amdgcn_mfma_f32_16x16x32_bf16(
                    af[mt], bfr[nti], acc[mt][nti], 0, 0, 0);
    }
    // epilogue 1: bias + swish -> sH1 (bf16)
#pragma unroll
    for (int mt = 0; mt < 4; mt++)
#pragma unroll
        for (int nti = 0; nti < 4; nti++) {
            const int o = (wv * 4 + nti) * 16 + l15;
            const float bias = b1[o];
#pragma unroll
            for (int r = 0; r < 4; r++) {
                float v = acc[mt][nti][r] + bias;
                float sw = v / (1.f + __expf(-v));
                sH1[(mt * 16 + g * 4 + r) * 520 + o] = f2bf(sw);
            }
        }
    __syncthreads();

    // ---- layer 2: K = 512 (16 ktiles) ----
#pragma unroll
    for (int i = 0; i < 4; i++)
#pragma unroll
        for (int j = 0; j < 4; j++) acc[i][j] = (f32x4){0.f, 0.f, 0.f, 0.f};

    const bf16x8* w2v = (const bf16x8*)(ws + OFF_W2P);
    for (int kt = 0; kt < 16; kt++) {
        bf16x8 af[4];
#pragma unroll
        for (int mt = 0; mt < 4; mt++) {
            const unsigned short* p = sH1 + (mt * 16 + l15) * 520 + kt * 32 + 4 * g;
            bf16x4 lo = *(const bf16x4*)p;
            bf16x4 hi = *(const bf16x4*)(p + 16);
            af[mt] = __builtin_shufflevector(lo, hi, 0, 1, 2, 3, 4, 5, 6, 7);
        }
        bf16x8 bfr[4];
#pragma unroll
        for (int nti = 0; nti < 4; nti++)
            bfr[nti] = w2v[((wv * 4 + nti) * 16 + kt) * 64 + lane];
#pragma unroll
        for (int mt = 0; mt < 4; mt++)
#pragma unroll
            for (int nti = 0; nti < 4; nti++)
                acc[mt][nti] = __builtin_amdgcn_mfma_f32_16x16x32_bf16(
                    af[mt], bfr[nti], acc[mt][nti], 0, 0, 0);
    }
    // epilogue 2: bias + swish + mean over the 64 samples
#pragma unroll
    for (int nti = 0; nti < 4; nti++) {
        float tot = 0.f;
        const int o = (wv * 4 + nti) * 16 + l15;
        const float bias = b2[o];
#pragma unroll
        for (int mt = 0; mt < 4; mt++) {
#pragma unroll
            for (int r = 0; r < 4; r++) {
                float v = acc[mt][nti][r] + bias;
                tot += v / (1.f + __expf(-v));
            }
        }
        tot += __shfl_xor(tot, 16);
        tot += __shfl_xor(tot, 32);
        if (lane < 16) {
            const int oo = (wv * 4 + nti) * 16 + lane;
            out[((size_t)b * 512 + oo) * 1024 + sq] = tot * 0.015625f;
        }
    }
}

extern "C" void kernel_launch(void* const* d_in, const int* in_sizes, int n_in,
                              void* d_out, int out_size, void* d_ws, size_t ws_size,
                              hipStream_t stream)
{
    const float* xyz = (const float*)d_in[0];
    const float* pts = (const float*)d_in[1];
    const float* w1  = (const float*)d_in[2];
    const float* b1  = (const float*)d_in[3];
    const float* w2  = (const float*)d_in[4];
    const float* b2  = (const float*)d_in[5];
    float* out = (float*)d_out;
    unsigned char* ws = (unsigned char*)d_ws;

    k_prep<<<1094, 1024, 0, stream>>>(xyz, pts, w1, w2, ws);
    k_ball<<<1024, 256, 0, stream>>>(xyz, ws);
    k_mlp<<<4096, 512, 0, stream>>>(xyz, b1, b2, ws, out);
}